// Round 1
// baseline (867.342 us; speedup 1.0000x reference)
//
#include <hip/hip_runtime.h>
#include <math.h>

#define S_LEN 2048
#define EMBED 512
#define HEADS 8
#define HDIM 64
#define BATCH 4
#define TOKENS (BATCH * S_LEN)
#define WINDOW 128

// ---------------------------------------------------------------------------
// Kernel 1: QKV projection GEMM with fused embedding gather.
// C[t][o] = sum_k emb[text[t]][k] * in_w[o][k] + in_b[o]
// scattered into q/k/v laid out as [B][H][S][64].
// 128x128 tile, 256 threads, 8x8 micro-tile (interleaved: rows ty+16i, cols tx+16j).
// ---------------------------------------------------------------------------
__global__ __launch_bounds__(256) void qkv_kernel(
    const int* __restrict__ text, const float* __restrict__ emb,
    const float* __restrict__ in_w, const float* __restrict__ in_b,
    float* __restrict__ qg, float* __restrict__ kg, float* __restrict__ vg) {
  __shared__ float As[128][36];
  __shared__ float Ws[128][36];
  const int m0 = blockIdx.x * 128;
  const int n0 = blockIdx.y * 128;
  const int tid = threadIdx.x;
  const int tx = tid & 15, ty = tid >> 4;
  const int lc4 = tid & 7, lr = tid >> 3;  // loader: 8 float4 cols x 32 row-groups

  float acc[8][8];
#pragma unroll
  for (int i = 0; i < 8; ++i)
#pragma unroll
    for (int j = 0; j < 8; ++j) acc[i][j] = 0.f;

  const float* arow[4];
  const float* wrow[4];
#pragma unroll
  for (int i = 0; i < 4; ++i) {
    arow[i] = emb + (size_t)text[m0 + lr + 32 * i] * EMBED;
    wrow[i] = in_w + (size_t)(n0 + lr + 32 * i) * EMBED;
  }

  for (int k0 = 0; k0 < EMBED; k0 += 32) {
#pragma unroll
    for (int i = 0; i < 4; ++i) {
      *(float4*)&As[lr + 32 * i][lc4 * 4] = *(const float4*)(arow[i] + k0 + lc4 * 4);
      *(float4*)&Ws[lr + 32 * i][lc4 * 4] = *(const float4*)(wrow[i] + k0 + lc4 * 4);
    }
    __syncthreads();
#pragma unroll
    for (int kk = 0; kk < 32; kk += 2) {
      float2 a2[8], b2[8];
#pragma unroll
      for (int i = 0; i < 8; ++i) a2[i] = *(const float2*)&As[ty + 16 * i][kk];
#pragma unroll
      for (int j = 0; j < 8; ++j) b2[j] = *(const float2*)&Ws[tx + 16 * j][kk];
#pragma unroll
      for (int i = 0; i < 8; ++i)
#pragma unroll
        for (int j = 0; j < 8; ++j) {
          acc[i][j] += a2[i].x * b2[j].x;
          acc[i][j] += a2[i].y * b2[j].y;
        }
    }
    __syncthreads();
  }

  // epilogue: add bias, scatter into q/k/v [B][H][S][D]
#pragma unroll
  for (int j = 0; j < 8; ++j) {
    const int o = n0 + tx + 16 * j;
    const float bias = in_b[o];
    const int sec = o >> 9;           // 0:q 1:k 2:v
    const int f = o & 511;
    const int h = f >> 6, d = f & 63;
    float* dst = (sec == 0) ? qg : ((sec == 1) ? kg : vg);
#pragma unroll
    for (int i = 0; i < 8; ++i) {
      const int t = m0 + ty + 16 * i;
      const int b = t >> 11, s = t & 2047;
      dst[((size_t)((b * HEADS + h) * S_LEN + s)) * HDIM + d] = acc[i][j] + bias;
    }
  }
}

// ---------------------------------------------------------------------------
// Kernel 2: banded attention. One block per (b*h, 32 query rows).
// Band for rows [i0, i0+31] covers j in [i0-128, i0+159] -> 288 columns.
// Exact softmax (scores fully materialized in LDS, 288 cols).
// ---------------------------------------------------------------------------
__global__ __launch_bounds__(256) void attn_kernel(
    const float* __restrict__ qg, const float* __restrict__ kg,
    const float* __restrict__ vg, float* __restrict__ attn) {
  __shared__ float Sx[32 * 289];   // scores/probs, stride 289
  __shared__ float Qs[32 * 66];    // Q tile (scaled), stride 66
  __shared__ float KVs[64 * 66];   // K or V tile, stride 66
  const int bh = blockIdx.y;
  const int i0 = blockIdx.x * 32;
  const int tid = threadIdx.x;
  const int tx = tid & 15, ty = tid >> 4;
  const size_t base = (size_t)bh * S_LEN * HDIM;
  const int jb = i0 - 128;

  // stage Q, pre-scaled by 1/sqrt(64)
  {
    const int c4 = tid & 15, r0 = tid >> 4;
#pragma unroll
    for (int rr = 0; rr < 2; ++rr) {
      const int r = r0 + 16 * rr;
      float4 a = *(const float4*)(qg + base + (size_t)(i0 + r) * HDIM + c4 * 4);
      Qs[r * 66 + c4 * 4 + 0] = a.x * 0.125f;
      Qs[r * 66 + c4 * 4 + 1] = a.y * 0.125f;
      Qs[r * 66 + c4 * 4 + 2] = a.z * 0.125f;
      Qs[r * 66 + c4 * 4 + 3] = a.w * 0.125f;
    }
  }

  // scores: 4 full tiles of 64 cols + 1 half tile of 32 cols
  for (int t = 0; t < 5; ++t) {
    const int nrows = (t < 4) ? 4 : 2;  // row-groups of 16 to stage
    __syncthreads();
    {
      const int c4 = tid & 15, r0 = tid >> 4;
      for (int rr = 0; rr < nrows; ++rr) {
        const int r = r0 + 16 * rr;
        const int gj = jb + t * 64 + r;
        float4 a = make_float4(0.f, 0.f, 0.f, 0.f);
        if (gj >= 0 && gj < S_LEN)
          a = *(const float4*)(kg + base + (size_t)gj * HDIM + c4 * 4);
        KVs[r * 66 + c4 * 4 + 0] = a.x;
        KVs[r * 66 + c4 * 4 + 1] = a.y;
        KVs[r * 66 + c4 * 4 + 2] = a.z;
        KVs[r * 66 + c4 * 4 + 3] = a.w;
      }
    }
    __syncthreads();
    const int njj = (t < 4) ? 4 : 2;
#pragma unroll
    for (int ii = 0; ii < 2; ++ii) {
      const int row = ty * 2 + ii;
      const int gi = i0 + row;
      float s[4] = {0.f, 0.f, 0.f, 0.f};
      for (int kk = 0; kk < HDIM; kk += 2) {
        const float2 qv = *(const float2*)&Qs[row * 66 + kk];
#pragma unroll
        for (int jj = 0; jj < 4; ++jj) {
          const float2 kv = *(const float2*)&KVs[(tx + 16 * jj) * 66 + kk];
          s[jj] += qv.x * kv.x;
          s[jj] += qv.y * kv.y;
        }
      }
      for (int jj = 0; jj < njj; ++jj) {
        const int c = t * 64 + tx + 16 * jj;
        const int gj = jb + c;
        const bool valid = (gj >= 0) && (gj < S_LEN) && (gj - gi <= WINDOW) && (gi - gj <= WINDOW);
        Sx[row * 289 + c] = valid ? s[jj] : -1e30f;
      }
    }
  }
  __syncthreads();

  // softmax: 8 lanes per row, each scans a contiguous 36-col chunk
  {
    const int row = tid >> 3, sub = tid & 7;
    float* srow = &Sx[row * 289 + sub * 36];
    float m = -1e30f;
    for (int ii = 0; ii < 36; ++ii) m = fmaxf(m, srow[ii]);
    m = fmaxf(m, __shfl_xor(m, 1));
    m = fmaxf(m, __shfl_xor(m, 2));
    m = fmaxf(m, __shfl_xor(m, 4));
    float l = 0.f;
    for (int ii = 0; ii < 36; ++ii) {
      const float e = __expf(srow[ii] - m);
      srow[ii] = e;
      l += e;
    }
    l += __shfl_xor(l, 1);
    l += __shfl_xor(l, 2);
    l += __shfl_xor(l, 4);
    const float linv = 1.0f / l;
    for (int ii = 0; ii < 36; ++ii) srow[ii] *= linv;
  }

  // PV: O[row][d] = sum_j P[row][j] * V[j][d]
  float o[2][4] = {{0.f, 0.f, 0.f, 0.f}, {0.f, 0.f, 0.f, 0.f}};
  for (int t = 0; t < 5; ++t) {
    const int nrows = (t < 4) ? 4 : 2;
    __syncthreads();
    {
      const int c4 = tid & 15, r0 = tid >> 4;
      for (int rr = 0; rr < nrows; ++rr) {
        const int r = r0 + 16 * rr;
        const int gj = jb + t * 64 + r;
        float4 a = make_float4(0.f, 0.f, 0.f, 0.f);
        if (gj >= 0 && gj < S_LEN)
          a = *(const float4*)(vg + base + (size_t)gj * HDIM + c4 * 4);
        KVs[r * 66 + c4 * 4 + 0] = a.x;
        KVs[r * 66 + c4 * 4 + 1] = a.y;
        KVs[r * 66 + c4 * 4 + 2] = a.z;
        KVs[r * 66 + c4 * 4 + 3] = a.w;
      }
    }
    __syncthreads();
    const int jmax = (t < 4) ? 64 : 32;
    for (int jj = 0; jj < jmax; ++jj) {
      const float p0 = Sx[(ty * 2 + 0) * 289 + t * 64 + jj];
      const float p1 = Sx[(ty * 2 + 1) * 289 + t * 64 + jj];
#pragma unroll
      for (int dd = 0; dd < 4; ++dd) {
        const float vv = KVs[jj * 66 + tx + 16 * dd];
        o[0][dd] += p0 * vv;
        o[1][dd] += p1 * vv;
      }
    }
  }

  const int b = bh >> 3, h = bh & 7;
#pragma unroll
  for (int ii = 0; ii < 2; ++ii) {
    const int gi = i0 + ty * 2 + ii;
#pragma unroll
    for (int dd = 0; dd < 4; ++dd)
      attn[((size_t)(b * S_LEN + gi)) * EMBED + h * HDIM + tx + 16 * dd] = o[ii][dd];
  }
}

// ---------------------------------------------------------------------------
// Kernel 3: out-projection GEMM + fused per-column max (over the 128-row tile).
// Never materializes attn @ out_w.T; writes partial maxes to pmax[b][stile][512].
// ---------------------------------------------------------------------------
__global__ __launch_bounds__(256) void outproj_kernel(
    const float* __restrict__ attn, const float* __restrict__ out_w,
    const float* __restrict__ out_b, float* __restrict__ pmax) {
  __shared__ float As[128][36];
  __shared__ float Ws[128][36];
  const int m0 = blockIdx.x * 128;
  const int n0 = blockIdx.y * 128;
  const int tid = threadIdx.x;
  const int tx = tid & 15, ty = tid >> 4;
  const int lc4 = tid & 7, lr = tid >> 3;

  float acc[8][8];
#pragma unroll
  for (int i = 0; i < 8; ++i)
#pragma unroll
    for (int j = 0; j < 8; ++j) acc[i][j] = 0.f;

  for (int k0 = 0; k0 < EMBED; k0 += 32) {
#pragma unroll
    for (int i = 0; i < 4; ++i) {
      *(float4*)&As[lr + 32 * i][lc4 * 4] =
          *(const float4*)(attn + (size_t)(m0 + lr + 32 * i) * EMBED + k0 + lc4 * 4);
      *(float4*)&Ws[lr + 32 * i][lc4 * 4] =
          *(const float4*)(out_w + (size_t)(n0 + lr + 32 * i) * EMBED + k0 + lc4 * 4);
    }
    __syncthreads();
#pragma unroll
    for (int kk = 0; kk < 32; kk += 2) {
      float2 a2[8], b2[8];
#pragma unroll
      for (int i = 0; i < 8; ++i) a2[i] = *(const float2*)&As[ty + 16 * i][kk];
#pragma unroll
      for (int j = 0; j < 8; ++j) b2[j] = *(const float2*)&Ws[tx + 16 * j][kk];
#pragma unroll
      for (int i = 0; i < 8; ++i)
#pragma unroll
        for (int j = 0; j < 8; ++j) {
          acc[i][j] += a2[i].x * b2[j].x;
          acc[i][j] += a2[i].y * b2[j].y;
        }
    }
    __syncthreads();
  }

  // per-thread column max over its 8 rows
  float cm[8];
#pragma unroll
  for (int j = 0; j < 8; ++j) {
    float m = -1e30f;
#pragma unroll
    for (int i = 0; i < 8; ++i) m = fmaxf(m, acc[i][j]);
    cm[j] = m;
  }
  // reduce across ty via LDS (reuse As)
  float* red = &As[0][0];
#pragma unroll
  for (int j = 0; j < 8; ++j) red[ty * 128 + tx + 16 * j] = cm[j];
  __syncthreads();
  if (tid < 128) {
    float m = -1e30f;
#pragma unroll
    for (int r = 0; r < 16; ++r) m = fmaxf(m, red[r * 128 + tid]);
    const int n = n0 + tid;
    const int b = m0 >> 11, stile = (m0 >> 7) & 15;
    pmax[(size_t)(b * 16 + stile) * 512 + n] = m + out_b[n];
  }
}

// ---------------------------------------------------------------------------
// Kernel 4: final max reduce + 4-layer MLP (batch=4), single block.
// ---------------------------------------------------------------------------
__global__ __launch_bounds__(1024) void mlp_kernel(
    const float* __restrict__ pmax,
    const float* __restrict__ w1, const float* __restrict__ b1,
    const float* __restrict__ w2, const float* __restrict__ b2,
    const float* __restrict__ w3, const float* __restrict__ b3,
    const float* __restrict__ w4, const float* __restrict__ b4,
    float* __restrict__ out) {
  __shared__ float ctx[BATCH * 512];
  __shared__ float h1[BATCH * 512];
  __shared__ float h2[BATCH * 256];
  __shared__ float h3[BATCH * 128];
  const int tid = threadIdx.x;

  for (int idx = tid; idx < BATCH * 512; idx += 1024) {
    const int b = idx >> 9, e = idx & 511;
    float m = -1e30f;
#pragma unroll
    for (int t = 0; t < 16; ++t) m = fmaxf(m, pmax[(size_t)(b * 16 + t) * 512 + e]);
    ctx[idx] = m;
  }
  __syncthreads();

  for (int idx = tid; idx < BATCH * 512; idx += 1024) {
    const int b = idx >> 9, o = idx & 511;
    float acc = b1[o];
    const float* wr = w1 + (size_t)o * 512;
    const float* xr = ctx + b * 512;
    for (int k = 0; k < 512; k += 4) {
      const float4 w = *(const float4*)(wr + k);
      const float4 x = *(const float4*)(xr + k);
      acc += w.x * x.x; acc += w.y * x.y; acc += w.z * x.z; acc += w.w * x.w;
    }
    h1[idx] = acc > 0.f ? acc : 0.01f * acc;
  }
  __syncthreads();

  for (int idx = tid; idx < BATCH * 256; idx += 1024) {
    const int b = idx >> 8, o = idx & 255;
    float acc = b2[o];
    const float* wr = w2 + (size_t)o * 512;
    const float* xr = h1 + b * 512;
    for (int k = 0; k < 512; k += 4) {
      const float4 w = *(const float4*)(wr + k);
      const float4 x = *(const float4*)(xr + k);
      acc += w.x * x.x; acc += w.y * x.y; acc += w.z * x.z; acc += w.w * x.w;
    }
    h2[idx] = acc > 0.f ? acc : 0.01f * acc;
  }
  __syncthreads();

  for (int idx = tid; idx < BATCH * 128; idx += 1024) {
    const int b = idx >> 7, o = idx & 127;
    float acc = b3[o];
    const float* wr = w3 + (size_t)o * 256;
    const float* xr = h2 + b * 256;
    for (int k = 0; k < 256; k += 4) {
      const float4 w = *(const float4*)(wr + k);
      const float4 x = *(const float4*)(xr + k);
      acc += w.x * x.x; acc += w.y * x.y; acc += w.z * x.z; acc += w.w * x.w;
    }
    h3[idx] = acc > 0.f ? acc : 0.01f * acc;
  }
  __syncthreads();

  for (int idx = tid; idx < BATCH * 20; idx += 1024) {
    const int b = idx / 20, o = idx % 20;
    float acc = b4[o];
    const float* wr = w4 + (size_t)o * 128;
    const float* xr = h3 + b * 128;
    for (int k = 0; k < 128; k += 4) {
      const float4 w = *(const float4*)(wr + k);
      const float4 x = *(const float4*)(xr + k);
      acc += w.x * x.x; acc += w.y * x.y; acc += w.z * x.z; acc += w.w * x.w;
    }
    out[idx] = acc;
  }
}

// ---------------------------------------------------------------------------
extern "C" void kernel_launch(void* const* d_in, const int* in_sizes, int n_in,
                              void* d_out, int out_size, void* d_ws, size_t ws_size,
                              hipStream_t stream) {
  (void)in_sizes; (void)n_in; (void)out_size; (void)ws_size;
  const int*   text  = (const int*)d_in[0];
  const float* emb   = (const float*)d_in[1];
  const float* in_w  = (const float*)d_in[2];
  const float* in_b  = (const float*)d_in[3];
  const float* out_w = (const float*)d_in[4];
  const float* out_b = (const float*)d_in[5];
  const float* w1 = (const float*)d_in[6];
  const float* b1 = (const float*)d_in[7];
  const float* w2 = (const float*)d_in[8];
  const float* b2 = (const float*)d_in[9];
  const float* w3 = (const float*)d_in[10];
  const float* b3 = (const float*)d_in[11];
  const float* w4 = (const float*)d_in[12];
  const float* b4 = (const float*)d_in[13];

  float* ws = (float*)d_ws;
  const size_t QKV_ELEMS = (size_t)TOKENS * HDIM * HEADS / HEADS * HEADS; // 4*8*2048*64
  float* qg   = ws;
  float* kg   = qg + 4194304;
  float* vg   = kg + 4194304;
  float* attn = vg + 4194304;
  float* pmax = attn + 4194304;
  (void)QKV_ELEMS;

  qkv_kernel<<<dim3(64, 12), 256, 0, stream>>>(text, emb, in_w, in_b, qg, kg, vg);
  attn_kernel<<<dim3(64, 32), 256, 0, stream>>>(qg, kg, vg, attn);
  outproj_kernel<<<dim3(64, 4), 256, 0, stream>>>(attn, out_w, out_b, pmax);
  mlp_kernel<<<1, 1024, 0, stream>>>(pmax, w1, b1, w2, b2, w3, b3, w4, b4,
                                     (float*)d_out);
}

// Round 2
// 282.780 us; speedup vs baseline: 3.0672x; 3.0672x over previous
//
#include <hip/hip_runtime.h>

typedef unsigned short u16;
typedef __attribute__((ext_vector_type(8))) short bf16x8;
typedef __attribute__((ext_vector_type(4))) float f32x4;

#define S_LEN 2048
#define EMBED 512
#define HEADS 8
#define HDIM 64
#define BATCH 4
#define TOKENS (BATCH * S_LEN)

__device__ __forceinline__ u16 f2bf(float f) {
  union { float f; unsigned u; } v;
  v.f = f;
  unsigned r = v.u + 0x7fffu + ((v.u >> 16) & 1u);
  return (u16)(r >> 16);
}

__device__ __forceinline__ void gl2lds16(const void* g, void* l) {
  __builtin_amdgcn_global_load_lds(
      (const __attribute__((address_space(1))) void*)g,
      (__attribute__((address_space(3))) void*)l, 16, 0, 0);
}

// ---------------------------------------------------------------------------
// Kernel A: gather emb rows -> Xb bf16 [8192][512]
// ---------------------------------------------------------------------------
__global__ __launch_bounds__(256) void gather_kernel(
    const int* __restrict__ text, const float* __restrict__ emb,
    u16* __restrict__ Xb) {
  const int t = blockIdx.x;
  const int tid = threadIdx.x;
  const size_t src = (size_t)text[t] * EMBED + tid * 2;
  const float2 v = *(const float2*)(emb + src);
  u16* dst = Xb + (size_t)t * EMBED + tid * 2;
  dst[0] = f2bf(v.x);
  dst[1] = f2bf(v.y);
}

// ---------------------------------------------------------------------------
// Kernel B: convert in_w (1536x512) and out_w (512x512) to bf16.
// ---------------------------------------------------------------------------
__global__ __launch_bounds__(256) void convw_kernel(
    const float* __restrict__ in_w, const float* __restrict__ out_w,
    u16* __restrict__ Wq, u16* __restrict__ Wo) {
  const int idx4 = (blockIdx.x * 256 + threadIdx.x) * 4;
  const float* src;
  u16* dst;
  if (idx4 < 1536 * 512) { src = in_w + idx4; dst = Wq + idx4; }
  else { src = out_w + (idx4 - 1536 * 512); dst = Wo + (idx4 - 1536 * 512); }
  const float4 v = *(const float4*)src;
  dst[0] = f2bf(v.x); dst[1] = f2bf(v.y); dst[2] = f2bf(v.z); dst[3] = f2bf(v.w);
}

// ---------------------------------------------------------------------------
// Kernel C: QKV GEMM (bf16 MFMA). C[t][n] = Xb[t][:] . Wq[n][:] + in_b[n].
// 128x128 tile, BK=64, 4 waves each computing a 64x64 quadrant (4x4 MFMA grid).
// XOR-swizzled LDS chunks (16B) so frag ds_read_b128 is 2-way-conflict (free).
// Epilogue: q scaled 0.125 -> qg[B][H][S][64]; k -> kg; v transposed -> vt[B][H][64][S].
// ---------------------------------------------------------------------------
__global__ __launch_bounds__(256, 3) void qkv_mfma(
    const u16* __restrict__ Xb, const u16* __restrict__ Wq,
    const float* __restrict__ in_b,
    u16* __restrict__ qg, u16* __restrict__ kg, u16* __restrict__ vt) {
  __shared__ u16 As[128 * 64];
  __shared__ u16 Bs[128 * 64];
  const int m0 = blockIdx.x * 128, n0 = blockIdx.y * 128;
  const int tid = threadIdx.x;
  const int w = tid >> 6, l = tid & 63, quad = l >> 4, ln = l & 15;
  const int rb = (w >> 1) * 64, cb = (w & 1) * 64;

  f32x4 acc[4][4] = {};

  for (int k0 = 0; k0 < EMBED; k0 += 64) {
#pragma unroll
    for (int it = 0; it < 4; ++it) {
      const int chunk = it * 256 + tid;
      const int row = chunk >> 3, cp = chunk & 7, c = cp ^ (row & 7);
      gl2lds16(Xb + (size_t)(m0 + row) * EMBED + k0 + c * 8, &As[chunk * 8]);
      gl2lds16(Wq + (size_t)(n0 + row) * EMBED + k0 + c * 8, &Bs[chunk * 8]);
    }
    __syncthreads();
#pragma unroll
    for (int s = 0; s < 2; ++s) {
      bf16x8 af[4], bf[4];
#pragma unroll
      for (int i = 0; i < 4; ++i) {
        const int r = rb + 16 * i + ln;
        af[i] = *(const bf16x8*)&As[r * 64 + (((s << 2) + quad) ^ (r & 7)) * 8];
      }
#pragma unroll
      for (int j = 0; j < 4; ++j) {
        const int n = cb + 16 * j + ln;
        bf[j] = *(const bf16x8*)&Bs[n * 64 + (((s << 2) + quad) ^ (n & 7)) * 8];
      }
#pragma unroll
      for (int i = 0; i < 4; ++i)
#pragma unroll
        for (int j = 0; j < 4; ++j)
          acc[i][j] = __builtin_amdgcn_mfma_f32_16x16x32_bf16(af[i], bf[j], acc[i][j], 0, 0, 0);
    }
    __syncthreads();
  }

#pragma unroll
  for (int j = 0; j < 4; ++j) {
    const int n = n0 + cb + 16 * j + ln;
    const float bias = in_b[n];
    const int sec = n >> 9, f = n & 511, h = f >> 6, d = f & 63;
#pragma unroll
    for (int i = 0; i < 4; ++i) {
#pragma unroll
      for (int r = 0; r < 4; ++r) {
        const int t = m0 + rb + 16 * i + quad * 4 + r;
        const int b = t >> 11, s = t & 2047;
        const float val = acc[i][j][r] + bias;
        if (sec == 0)
          qg[((size_t)((b * HEADS + h) * S_LEN + s)) * HDIM + d] = f2bf(val * 0.125f);
        else if (sec == 1)
          kg[((size_t)((b * HEADS + h) * S_LEN + s)) * HDIM + d] = f2bf(val);
        else
          vt[((size_t)((b * HEADS + h) * HDIM + d)) * S_LEN + s] = f2bf(val);
      }
    }
  }
}

// ---------------------------------------------------------------------------
// Kernel D: banded attention, MFMA. Block = (64 query rows) x (b,h).
// Band cols jb..jb+319. Scores in 80 C-layout VGPRs per wave; softmax in regs
// + shfl; P -> A-frag via per-wave LDS chunk; PV with V^T B-frags.
// KV region (40KB) staged twice: K band then V^T band.
// ---------------------------------------------------------------------------
__global__ __launch_bounds__(256, 3) void attn_mfma(
    const u16* __restrict__ qg, const u16* __restrict__ kg,
    const u16* __restrict__ vt, u16* __restrict__ attnb) {
  __shared__ u16 KV[320 * 64];      // 40 KB
  __shared__ u16 Pb[4][16 * 40];    // 5 KB, per-wave P chunk (stride 40 for b128 align)
  const int bh = blockIdx.y;
  const int i0 = blockIdx.x * 64;
  const int jb = i0 - 128;
  const int tid = threadIdx.x;
  const int w = tid >> 6, l = tid & 63, quad = l >> 4, ln = l & 15;

  // Q A-frags: rows i0 + w*16 + ln, k = s*32 + quad*8
  const u16* qrow = qg + ((size_t)bh * S_LEN + i0 + w * 16 + ln) * HDIM;
  bf16x8 qf[2];
  qf[0] = *(const bf16x8*)(qrow + quad * 8);
  qf[1] = *(const bf16x8*)(qrow + 32 + quad * 8);

  // stage K band [320 rows][8 chunks], swizzled
  const u16* kbase = kg + (size_t)bh * S_LEN * HDIM;
#pragma unroll
  for (int it = 0; it < 10; ++it) {
    const int chunk = it * 256 + tid;
    const int row = chunk >> 3, cp = chunk & 7, c = cp ^ (row & 7);
    int gj = jb + row;
    gj = gj < 0 ? 0 : (gj > S_LEN - 1 ? S_LEN - 1 : gj);
    gl2lds16(kbase + (size_t)gj * HDIM + c * 8, &KV[chunk * 8]);
  }
  __syncthreads();

  // scores: 20 col-tiles of 16
  f32x4 sc[20];
#pragma unroll
  for (int jt = 0; jt < 20; ++jt) {
    const int r = jt * 16 + ln;
    const bf16x8 b0 = *(const bf16x8*)&KV[r * 64 + ((quad) ^ (r & 7)) * 8];
    const bf16x8 b1 = *(const bf16x8*)&KV[r * 64 + ((4 + quad) ^ (r & 7)) * 8];
    f32x4 a = {};
    a = __builtin_amdgcn_mfma_f32_16x16x32_bf16(qf[0], b0, a, 0, 0, 0);
    a = __builtin_amdgcn_mfma_f32_16x16x32_bf16(qf[1], b1, a, 0, 0, 0);
    sc[jt] = a;
  }
  __syncthreads();  // K reads done; KV region free

  // stage V^T band [64 rows(d)][40 chunks(j)], swizzled; overlap with softmax
  const u16* vbase = vt + (size_t)bh * HDIM * S_LEN;
#pragma unroll
  for (int it = 0; it < 10; ++it) {
    const int chunk = it * 256 + tid;
    const int row = chunk / 40, cp = chunk % 40, c = cp ^ (row & 7);
    int gc = jb + c * 8;
    gc = gc < 0 ? 0 : (gc > S_LEN - 8 ? S_LEN - 8 : gc);
    gl2lds16(vbase + (size_t)row * S_LEN + gc, &KV[chunk * 8]);
  }

  // mask + softmax (rows gi = i0 + w*16 + quad*4 + r; cols gj = jb + jt*16 + ln)
  const int gibase = i0 + w * 16 + quad * 4;
  float mrow[4] = {-1e30f, -1e30f, -1e30f, -1e30f}, lrow[4];
#pragma unroll
  for (int jt = 0; jt < 20; ++jt) {
    const int gj = jb + jt * 16 + ln;
#pragma unroll
    for (int r = 0; r < 4; ++r) {
      const int dij = (gibase + r) - gj;
      const bool valid = (gj >= 0) && (gj < S_LEN) && (dij <= 128) && (dij >= -128);
      const float v = valid ? sc[jt][r] : -1e30f;
      sc[jt][r] = v;
      mrow[r] = fmaxf(mrow[r], v);
    }
  }
#pragma unroll
  for (int r = 0; r < 4; ++r) {
    mrow[r] = fmaxf(mrow[r], __shfl_xor(mrow[r], 1));
    mrow[r] = fmaxf(mrow[r], __shfl_xor(mrow[r], 2));
    mrow[r] = fmaxf(mrow[r], __shfl_xor(mrow[r], 4));
    mrow[r] = fmaxf(mrow[r], __shfl_xor(mrow[r], 8));
    lrow[r] = 0.f;
  }
#pragma unroll
  for (int jt = 0; jt < 20; ++jt)
#pragma unroll
    for (int r = 0; r < 4; ++r) {
      const float e = __expf(sc[jt][r] - mrow[r]);
      sc[jt][r] = e;
      lrow[r] += e;
    }
#pragma unroll
  for (int r = 0; r < 4; ++r) {
    lrow[r] += __shfl_xor(lrow[r], 1);
    lrow[r] += __shfl_xor(lrow[r], 2);
    lrow[r] += __shfl_xor(lrow[r], 4);
    lrow[r] += __shfl_xor(lrow[r], 8);
    lrow[r] = 1.0f / lrow[r];
  }
#pragma unroll
  for (int jt = 0; jt < 20; ++jt)
#pragma unroll
    for (int r = 0; r < 4; ++r) sc[jt][r] *= lrow[r];

  __syncthreads();  // V^T staged

  // PV: O[64][64] per block; per wave 16-row strip, 10 k-chunks of 32
  f32x4 oacc[4] = {};
  u16* pb = &Pb[w][0];
#pragma unroll
  for (int kt = 0; kt < 10; ++kt) {
#pragma unroll
    for (int tt = 0; tt < 2; ++tt) {
      const int jt = kt * 2 + tt;
#pragma unroll
      for (int r = 0; r < 4; ++r)
        pb[(quad * 4 + r) * 40 + ln + 16 * tt] = f2bf(sc[jt][r]);
    }
    __asm__ volatile("" ::: "memory");  // keep write->read order
    const bf16x8 pa = *(const bf16x8*)&pb[ln * 40 + quad * 8];
#pragma unroll
    for (int dt = 0; dt < 4; ++dt) {
      const int d = dt * 16 + ln;
      const bf16x8 vb = *(const bf16x8*)&KV[d * 320 + ((kt * 4 + quad) ^ (d & 7)) * 8];
      oacc[dt] = __builtin_amdgcn_mfma_f32_16x16x32_bf16(pa, vb, oacc[dt], 0, 0, 0);
    }
  }

  // write O (bf16) to attn [B][S][512]
  const int b = bh >> 3, h = bh & 7;
#pragma unroll
  for (int dt = 0; dt < 4; ++dt) {
    const int d = h * HDIM + dt * 16 + ln;
#pragma unroll
    for (int r = 0; r < 4; ++r) {
      const int gi = i0 + w * 16 + quad * 4 + r;
      attnb[((size_t)(b * S_LEN + gi)) * EMBED + d] = f2bf(oacc[dt][r]);
    }
  }
}

// ---------------------------------------------------------------------------
// Kernel E: out-projection GEMM (bf16 MFMA) + fused column max over 128-row tile.
// pmax[b*16+stile][n] = max_rows(attn @ out_w.T) + out_b[n]
// ---------------------------------------------------------------------------
__global__ __launch_bounds__(256, 3) void outproj_mfma(
    const u16* __restrict__ attnb, const u16* __restrict__ Wo,
    const float* __restrict__ out_b, float* __restrict__ pmax) {
  __shared__ u16 As[128 * 64];
  __shared__ u16 Bs[128 * 64];
  __shared__ float red[4][64];
  const int m0 = blockIdx.x * 128, n0 = blockIdx.y * 128;
  const int tid = threadIdx.x;
  const int w = tid >> 6, l = tid & 63, quad = l >> 4, ln = l & 15;
  const int rb = (w >> 1) * 64, cb = (w & 1) * 64;

  f32x4 acc[4][4] = {};

  for (int k0 = 0; k0 < EMBED; k0 += 64) {
#pragma unroll
    for (int it = 0; it < 4; ++it) {
      const int chunk = it * 256 + tid;
      const int row = chunk >> 3, cp = chunk & 7, c = cp ^ (row & 7);
      gl2lds16(attnb + (size_t)(m0 + row) * EMBED + k0 + c * 8, &As[chunk * 8]);
      gl2lds16(Wo + (size_t)(n0 + row) * EMBED + k0 + c * 8, &Bs[chunk * 8]);
    }
    __syncthreads();
#pragma unroll
    for (int s = 0; s < 2; ++s) {
      bf16x8 af[4], bf[4];
#pragma unroll
      for (int i = 0; i < 4; ++i) {
        const int r = rb + 16 * i + ln;
        af[i] = *(const bf16x8*)&As[r * 64 + (((s << 2) + quad) ^ (r & 7)) * 8];
      }
#pragma unroll
      for (int j = 0; j < 4; ++j) {
        const int n = cb + 16 * j + ln;
        bf[j] = *(const bf16x8*)&Bs[n * 64 + (((s << 2) + quad) ^ (n & 7)) * 8];
      }
#pragma unroll
      for (int i = 0; i < 4; ++i)
#pragma unroll
        for (int j = 0; j < 4; ++j)
          acc[i][j] = __builtin_amdgcn_mfma_f32_16x16x32_bf16(af[i], bf[j], acc[i][j], 0, 0, 0);
    }
    __syncthreads();
  }

  // column max within wave quadrant (64 rows x 64 cols)
  float cm[4];
#pragma unroll
  for (int j = 0; j < 4; ++j) {
    float m = -1e30f;
#pragma unroll
    for (int i = 0; i < 4; ++i)
#pragma unroll
      for (int r = 0; r < 4; ++r) m = fmaxf(m, acc[i][j][r]);
    m = fmaxf(m, __shfl_xor(m, 16));
    m = fmaxf(m, __shfl_xor(m, 32));
    cm[j] = m;
  }
  if (l < 16) {
#pragma unroll
    for (int j = 0; j < 4; ++j) red[w][ln + 16 * j] = cm[j];
  }
  __syncthreads();
  if (tid < 128) {
    const int ch = tid >> 6, cw = tid & 63;
    const float m = fmaxf(red[ch][cw], red[ch + 2][cw]);
    const int n = n0 + ch * 64 + cw;
    const int b = m0 >> 11, stile = (m0 >> 7) & 15;
    pmax[(size_t)(b * 16 + stile) * EMBED + n] = m + out_b[n];
  }
}

// ---------------------------------------------------------------------------
// Kernel F: final max reduce + 4-layer MLP, fp32. One block per batch element.
// ---------------------------------------------------------------------------
__global__ __launch_bounds__(1024) void mlp_kernel(
    const float* __restrict__ pmax,
    const float* __restrict__ w1, const float* __restrict__ b1,
    const float* __restrict__ w2, const float* __restrict__ b2,
    const float* __restrict__ w3, const float* __restrict__ b3,
    const float* __restrict__ w4, const float* __restrict__ b4,
    float* __restrict__ out) {
  __shared__ float ctx[512], h1[512], h2[256], h3[128];
  const int b = blockIdx.x, tid = threadIdx.x;

  if (tid < 512) {
    float m = -1e30f;
#pragma unroll
    for (int t = 0; t < 16; ++t) m = fmaxf(m, pmax[(size_t)(b * 16 + t) * 512 + tid]);
    ctx[tid] = m;
  }
  __syncthreads();

  {  // layer1: 512 outs x 2 threads (k-half 256)
    const int o = tid >> 1, kh = tid & 1;
    float acc = 0.f;
    const float* wr = w1 + (size_t)o * 512 + kh * 256;
    const float* xr = ctx + kh * 256;
    for (int k = 0; k < 256; k += 4) {
      const float4 wv = *(const float4*)(wr + k);
      const float4 xv = *(const float4*)(xr + k);
      acc += wv.x * xv.x + wv.y * xv.y + wv.z * xv.z + wv.w * xv.w;
    }
    acc += __shfl_xor(acc, 1);
    if (kh == 0) { const float a = acc + b1[o]; h1[o] = a > 0.f ? a : 0.01f * a; }
  }
  __syncthreads();

  {  // layer2: 256 outs x 4 threads (k 128)
    const int o = tid >> 2, kq = tid & 3;
    float acc = 0.f;
    const float* wr = w2 + (size_t)o * 512 + kq * 128;
    const float* xr = h1 + kq * 128;
    for (int k = 0; k < 128; k += 4) {
      const float4 wv = *(const float4*)(wr + k);
      const float4 xv = *(const float4*)(xr + k);
      acc += wv.x * xv.x + wv.y * xv.y + wv.z * xv.z + wv.w * xv.w;
    }
    acc += __shfl_xor(acc, 1);
    acc += __shfl_xor(acc, 2);
    if (kq == 0) { const float a = acc + b2[o]; h2[o] = a > 0.f ? a : 0.01f * a; }
  }
  __syncthreads();

  {  // layer3: 128 outs x 8 threads (k 32)
    const int o = tid >> 3, kq = tid & 7;
    float acc = 0.f;
    const float* wr = w3 + (size_t)o * 256 + kq * 32;
    const float* xr = h2 + kq * 32;
    for (int k = 0; k < 32; k += 4) {
      const float4 wv = *(const float4*)(wr + k);
      const float4 xv = *(const float4*)(xr + k);
      acc += wv.x * xv.x + wv.y * xv.y + wv.z * xv.z + wv.w * xv.w;
    }
    acc += __shfl_xor(acc, 1);
    acc += __shfl_xor(acc, 2);
    acc += __shfl_xor(acc, 4);
    if (kq == 0) { const float a = acc + b3[o]; h3[o] = a > 0.f ? a : 0.01f * a; }
  }
  __syncthreads();

  if (tid < 640) {  // layer4: 20 outs x 32 threads (k 4)
    const int o = tid >> 5, ks = tid & 31;
    const float* wr = w4 + (size_t)o * 128 + ks * 4;
    const float* xr = h3 + ks * 4;
    float acc = wr[0] * xr[0] + wr[1] * xr[1] + wr[2] * xr[2] + wr[3] * xr[3];
    acc += __shfl_xor(acc, 1);
    acc += __shfl_xor(acc, 2);
    acc += __shfl_xor(acc, 4);
    acc += __shfl_xor(acc, 8);
    acc += __shfl_xor(acc, 16);
    if (ks == 0) out[b * 20 + o] = acc + b4[o];
  }
}

// ---------------------------------------------------------------------------
extern "C" void kernel_launch(void* const* d_in, const int* in_sizes, int n_in,
                              void* d_out, int out_size, void* d_ws, size_t ws_size,
                              hipStream_t stream) {
  (void)in_sizes; (void)n_in; (void)out_size; (void)ws_size;
  const int*   text  = (const int*)d_in[0];
  const float* emb   = (const float*)d_in[1];
  const float* in_w  = (const float*)d_in[2];
  const float* in_b  = (const float*)d_in[3];
  const float* out_w = (const float*)d_in[4];
  const float* out_b = (const float*)d_in[5];
  const float* w1 = (const float*)d_in[6];
  const float* b1 = (const float*)d_in[7];
  const float* w2 = (const float*)d_in[8];
  const float* b2 = (const float*)d_in[9];
  const float* w3 = (const float*)d_in[10];
  const float* b3 = (const float*)d_in[11];
  const float* w4 = (const float*)d_in[12];
  const float* b4 = (const float*)d_in[13];

  char* ws = (char*)d_ws;
  u16* Xb   = (u16*)(ws);                       // 8192*512*2   = 8388608
  u16* Wq   = (u16*)(ws + 8388608);             // 1536*512*2   = 1572864
  u16* Wo   = (u16*)(ws + 9961472);             // 512*512*2    = 524288
  u16* qg   = (u16*)(ws + 10485760);            // 4M*2         = 8388608
  u16* kg   = (u16*)(ws + 18874368);
  u16* vt   = (u16*)(ws + 27262976);
  u16* attn = (u16*)(ws + 35651584);
  float* pmax = (float*)(ws + 44040192);        // 4*16*512*4   = 131072

  gather_kernel<<<TOKENS, 256, 0, stream>>>(text, emb, Xb);
  convw_kernel<<<1024, 256, 0, stream>>>(in_w, out_w, Wq, Wo);
  qkv_mfma<<<dim3(64, 12), 256, 0, stream>>>(Xb, Wq, in_b, qg, kg, vt);
  attn_mfma<<<dim3(32, 32), 256, 0, stream>>>(qg, kg, vt, attn);
  outproj_mfma<<<dim3(64, 4), 256, 0, stream>>>(attn, Wo, out_b, pmax);
  mlp_kernel<<<4, 1024, 0, stream>>>(pmax, w1, b1, w2, b2, w3, b3, w4, b4,
                                     (float*)d_out);
}

// Round 3
// 240.485 us; speedup vs baseline: 3.6066x; 1.1759x over previous
//
#include <hip/hip_runtime.h>

typedef unsigned short u16;
typedef __attribute__((ext_vector_type(8))) short bf16x8;
typedef __attribute__((ext_vector_type(4))) float f32x4;

#define S_LEN 2048
#define EMBED 512
#define HEADS 8
#define HDIM 64
#define BATCH 4
#define TOKENS (BATCH * S_LEN)

__device__ __forceinline__ u16 f2bf(float f) {
  union { float f; unsigned u; } v;
  v.f = f;
  unsigned r = v.u + 0x7fffu + ((v.u >> 16) & 1u);
  return (u16)(r >> 16);
}

__device__ __forceinline__ void gl2lds16(const void* g, void* l) {
  __builtin_amdgcn_global_load_lds(
      (const __attribute__((address_space(1))) void*)g,
      (__attribute__((address_space(3))) void*)l, 16, 0, 0);
}

// ---------------------------------------------------------------------------
// Kernel A: gather emb rows -> Xb bf16 [8192][512]
// ---------------------------------------------------------------------------
__global__ __launch_bounds__(256) void gather_kernel(
    const int* __restrict__ text, const float* __restrict__ emb,
    u16* __restrict__ Xb) {
  const int t = blockIdx.x;
  const int tid = threadIdx.x;
  const size_t src = (size_t)text[t] * EMBED + tid * 2;
  const float2 v = *(const float2*)(emb + src);
  u16* dst = Xb + (size_t)t * EMBED + tid * 2;
  dst[0] = f2bf(v.x);
  dst[1] = f2bf(v.y);
}

// ---------------------------------------------------------------------------
// Kernel B: convert in_w (1536x512) and out_w (512x512) to bf16.
// ---------------------------------------------------------------------------
__global__ __launch_bounds__(256) void convw_kernel(
    const float* __restrict__ in_w, const float* __restrict__ out_w,
    u16* __restrict__ Wq, u16* __restrict__ Wo) {
  const int idx4 = (blockIdx.x * 256 + threadIdx.x) * 4;
  const float* src;
  u16* dst;
  if (idx4 < 1536 * 512) { src = in_w + idx4; dst = Wq + idx4; }
  else { src = out_w + (idx4 - 1536 * 512); dst = Wo + (idx4 - 1536 * 512); }
  const float4 v = *(const float4*)src;
  dst[0] = f2bf(v.x); dst[1] = f2bf(v.y); dst[2] = f2bf(v.z); dst[3] = f2bf(v.w);
}

// ---------------------------------------------------------------------------
// Kernel C: QKV GEMM (bf16 MFMA). 128x128 tile, BK=64, 4 waves, 4x4 MFMA grid.
// ---------------------------------------------------------------------------
__global__ __launch_bounds__(256, 3) void qkv_mfma(
    const u16* __restrict__ Xb, const u16* __restrict__ Wq,
    const float* __restrict__ in_b,
    u16* __restrict__ qg, u16* __restrict__ kg, u16* __restrict__ vt) {
  __shared__ u16 As[128 * 64];
  __shared__ u16 Bs[128 * 64];
  const int m0 = blockIdx.x * 128, n0 = blockIdx.y * 128;
  const int tid = threadIdx.x;
  const int w = tid >> 6, l = tid & 63, quad = l >> 4, ln = l & 15;
  const int rb = (w >> 1) * 64, cb = (w & 1) * 64;

  f32x4 acc[4][4] = {};

  for (int k0 = 0; k0 < EMBED; k0 += 64) {
#pragma unroll
    for (int it = 0; it < 4; ++it) {
      const int chunk = it * 256 + tid;
      const int row = chunk >> 3, cp = chunk & 7, c = cp ^ (row & 7);
      gl2lds16(Xb + (size_t)(m0 + row) * EMBED + k0 + c * 8, &As[chunk * 8]);
      gl2lds16(Wq + (size_t)(n0 + row) * EMBED + k0 + c * 8, &Bs[chunk * 8]);
    }
    __syncthreads();
#pragma unroll
    for (int s = 0; s < 2; ++s) {
      bf16x8 af[4], bf[4];
#pragma unroll
      for (int i = 0; i < 4; ++i) {
        const int r = rb + 16 * i + ln;
        af[i] = *(const bf16x8*)&As[r * 64 + (((s << 2) + quad) ^ (r & 7)) * 8];
      }
#pragma unroll
      for (int j = 0; j < 4; ++j) {
        const int n = cb + 16 * j + ln;
        bf[j] = *(const bf16x8*)&Bs[n * 64 + (((s << 2) + quad) ^ (n & 7)) * 8];
      }
#pragma unroll
      for (int i = 0; i < 4; ++i)
#pragma unroll
        for (int j = 0; j < 4; ++j)
          acc[i][j] = __builtin_amdgcn_mfma_f32_16x16x32_bf16(af[i], bf[j], acc[i][j], 0, 0, 0);
    }
    __syncthreads();
  }

#pragma unroll
  for (int j = 0; j < 4; ++j) {
    const int n = n0 + cb + 16 * j + ln;
    const float bias = in_b[n];
    const int sec = n >> 9, f = n & 511, h = f >> 6, d = f & 63;
#pragma unroll
    for (int i = 0; i < 4; ++i) {
#pragma unroll
      for (int r = 0; r < 4; ++r) {
        const int t = m0 + rb + 16 * i + quad * 4 + r;
        const int b = t >> 11, s = t & 2047;
        const float val = acc[i][j][r] + bias;
        if (sec == 0)
          qg[((size_t)((b * HEADS + h) * S_LEN + s)) * HDIM + d] = f2bf(val * 0.125f);
        else if (sec == 1)
          kg[((size_t)((b * HEADS + h) * S_LEN + s)) * HDIM + d] = f2bf(val);
        else
          vt[((size_t)((b * HEADS + h) * HDIM + d)) * S_LEN + s] = f2bf(val);
      }
    }
  }
}

// ---------------------------------------------------------------------------
// Kernel D: banded attention, MFMA. Block = (64 query rows) x (b,h).
// ---------------------------------------------------------------------------
__global__ __launch_bounds__(256, 3) void attn_mfma(
    const u16* __restrict__ qg, const u16* __restrict__ kg,
    const u16* __restrict__ vt, u16* __restrict__ attnb) {
  __shared__ u16 KV[320 * 64];      // 40 KB
  __shared__ u16 Pb[4][16 * 40];    // 5 KB, per-wave P chunk
  const int bh = blockIdx.y;
  const int i0 = blockIdx.x * 64;
  const int jb = i0 - 128;
  const int tid = threadIdx.x;
  const int w = tid >> 6, l = tid & 63, quad = l >> 4, ln = l & 15;

  const u16* qrow = qg + ((size_t)bh * S_LEN + i0 + w * 16 + ln) * HDIM;
  bf16x8 qf[2];
  qf[0] = *(const bf16x8*)(qrow + quad * 8);
  qf[1] = *(const bf16x8*)(qrow + 32 + quad * 8);

  const u16* kbase = kg + (size_t)bh * S_LEN * HDIM;
#pragma unroll
  for (int it = 0; it < 10; ++it) {
    const int chunk = it * 256 + tid;
    const int row = chunk >> 3, cp = chunk & 7, c = cp ^ (row & 7);
    int gj = jb + row;
    gj = gj < 0 ? 0 : (gj > S_LEN - 1 ? S_LEN - 1 : gj);
    gl2lds16(kbase + (size_t)gj * HDIM + c * 8, &KV[chunk * 8]);
  }
  __syncthreads();

  f32x4 sc[20];
#pragma unroll
  for (int jt = 0; jt < 20; ++jt) {
    const int r = jt * 16 + ln;
    const bf16x8 b0 = *(const bf16x8*)&KV[r * 64 + ((quad) ^ (r & 7)) * 8];
    const bf16x8 b1 = *(const bf16x8*)&KV[r * 64 + ((4 + quad) ^ (r & 7)) * 8];
    f32x4 a = {};
    a = __builtin_amdgcn_mfma_f32_16x16x32_bf16(qf[0], b0, a, 0, 0, 0);
    a = __builtin_amdgcn_mfma_f32_16x16x32_bf16(qf[1], b1, a, 0, 0, 0);
    sc[jt] = a;
  }
  __syncthreads();

  const u16* vbase = vt + (size_t)bh * HDIM * S_LEN;
#pragma unroll
  for (int it = 0; it < 10; ++it) {
    const int chunk = it * 256 + tid;
    const int row = chunk / 40, cp = chunk % 40, c = cp ^ (row & 7);
    int gc = jb + c * 8;
    gc = gc < 0 ? 0 : (gc > S_LEN - 8 ? S_LEN - 8 : gc);
    gl2lds16(vbase + (size_t)row * S_LEN + gc, &KV[chunk * 8]);
  }

  const int gibase = i0 + w * 16 + quad * 4;
  float mrow[4] = {-1e30f, -1e30f, -1e30f, -1e30f}, lrow[4];
#pragma unroll
  for (int jt = 0; jt < 20; ++jt) {
    const int gj = jb + jt * 16 + ln;
#pragma unroll
    for (int r = 0; r < 4; ++r) {
      const int dij = (gibase + r) - gj;
      const bool valid = (gj >= 0) && (gj < S_LEN) && (dij <= 128) && (dij >= -128);
      const float v = valid ? sc[jt][r] : -1e30f;
      sc[jt][r] = v;
      mrow[r] = fmaxf(mrow[r], v);
    }
  }
#pragma unroll
  for (int r = 0; r < 4; ++r) {
    mrow[r] = fmaxf(mrow[r], __shfl_xor(mrow[r], 1));
    mrow[r] = fmaxf(mrow[r], __shfl_xor(mrow[r], 2));
    mrow[r] = fmaxf(mrow[r], __shfl_xor(mrow[r], 4));
    mrow[r] = fmaxf(mrow[r], __shfl_xor(mrow[r], 8));
    lrow[r] = 0.f;
  }
#pragma unroll
  for (int jt = 0; jt < 20; ++jt)
#pragma unroll
    for (int r = 0; r < 4; ++r) {
      const float e = __expf(sc[jt][r] - mrow[r]);
      sc[jt][r] = e;
      lrow[r] += e;
    }
#pragma unroll
  for (int r = 0; r < 4; ++r) {
    lrow[r] += __shfl_xor(lrow[r], 1);
    lrow[r] += __shfl_xor(lrow[r], 2);
    lrow[r] += __shfl_xor(lrow[r], 4);
    lrow[r] += __shfl_xor(lrow[r], 8);
    lrow[r] = 1.0f / lrow[r];
  }
#pragma unroll
  for (int jt = 0; jt < 20; ++jt)
#pragma unroll
    for (int r = 0; r < 4; ++r) sc[jt][r] *= lrow[r];

  __syncthreads();

  f32x4 oacc[4] = {};
  u16* pb = &Pb[w][0];
#pragma unroll
  for (int kt = 0; kt < 10; ++kt) {
#pragma unroll
    for (int tt = 0; tt < 2; ++tt) {
      const int jt = kt * 2 + tt;
#pragma unroll
      for (int r = 0; r < 4; ++r)
        pb[(quad * 4 + r) * 40 + ln + 16 * tt] = f2bf(sc[jt][r]);
    }
    __asm__ volatile("" ::: "memory");
    const bf16x8 pa = *(const bf16x8*)&pb[ln * 40 + quad * 8];
#pragma unroll
    for (int dt = 0; dt < 4; ++dt) {
      const int d = dt * 16 + ln;
      const bf16x8 vb = *(const bf16x8*)&KV[d * 320 + ((kt * 4 + quad) ^ (d & 7)) * 8];
      oacc[dt] = __builtin_amdgcn_mfma_f32_16x16x32_bf16(pa, vb, oacc[dt], 0, 0, 0);
    }
  }

  const int b = bh >> 3, h = bh & 7;
#pragma unroll
  for (int dt = 0; dt < 4; ++dt) {
    const int d = h * HDIM + dt * 16 + ln;
#pragma unroll
    for (int r = 0; r < 4; ++r) {
      const int gi = i0 + w * 16 + quad * 4 + r;
      attnb[((size_t)(b * S_LEN + gi)) * EMBED + d] = f2bf(oacc[dt][r]);
    }
  }
}

// ---------------------------------------------------------------------------
// Kernel E: out-projection GEMM (bf16 MFMA) + fused column max.
// ---------------------------------------------------------------------------
__global__ __launch_bounds__(256, 3) void outproj_mfma(
    const u16* __restrict__ attnb, const u16* __restrict__ Wo,
    const float* __restrict__ out_b, float* __restrict__ pmax) {
  __shared__ u16 As[128 * 64];
  __shared__ u16 Bs[128 * 64];
  __shared__ float red[4][64];
  const int m0 = blockIdx.x * 128, n0 = blockIdx.y * 128;
  const int tid = threadIdx.x;
  const int w = tid >> 6, l = tid & 63, quad = l >> 4, ln = l & 15;
  const int rb = (w >> 1) * 64, cb = (w & 1) * 64;

  f32x4 acc[4][4] = {};

  for (int k0 = 0; k0 < EMBED; k0 += 64) {
#pragma unroll
    for (int it = 0; it < 4; ++it) {
      const int chunk = it * 256 + tid;
      const int row = chunk >> 3, cp = chunk & 7, c = cp ^ (row & 7);
      gl2lds16(attnb + (size_t)(m0 + row) * EMBED + k0 + c * 8, &As[chunk * 8]);
      gl2lds16(Wo + (size_t)(n0 + row) * EMBED + k0 + c * 8, &Bs[chunk * 8]);
    }
    __syncthreads();
#pragma unroll
    for (int s = 0; s < 2; ++s) {
      bf16x8 af[4], bf[4];
#pragma unroll
      for (int i = 0; i < 4; ++i) {
        const int r = rb + 16 * i + ln;
        af[i] = *(const bf16x8*)&As[r * 64 + (((s << 2) + quad) ^ (r & 7)) * 8];
      }
#pragma unroll
      for (int j = 0; j < 4; ++j) {
        const int n = cb + 16 * j + ln;
        bf[j] = *(const bf16x8*)&Bs[n * 64 + (((s << 2) + quad) ^ (n & 7)) * 8];
      }
#pragma unroll
      for (int i = 0; i < 4; ++i)
#pragma unroll
        for (int j = 0; j < 4; ++j)
          acc[i][j] = __builtin_amdgcn_mfma_f32_16x16x32_bf16(af[i], bf[j], acc[i][j], 0, 0, 0);
    }
    __syncthreads();
  }

  float cm[4];
#pragma unroll
  for (int j = 0; j < 4; ++j) {
    float m = -1e30f;
#pragma unroll
    for (int i = 0; i < 4; ++i)
#pragma unroll
      for (int r = 0; r < 4; ++r) m = fmaxf(m, acc[i][j][r]);
    m = fmaxf(m, __shfl_xor(m, 16));
    m = fmaxf(m, __shfl_xor(m, 32));
    cm[j] = m;
  }
  if (l < 16) {
#pragma unroll
    for (int j = 0; j < 4; ++j) red[w][ln + 16 * j] = cm[j];
  }
  __syncthreads();
  if (tid < 128) {
    const int ch = tid >> 6, cw = tid & 63;
    const float m = fmaxf(red[ch][cw], red[ch + 2][cw]);
    const int n = n0 + ch * 64 + cw;
    const int b = m0 >> 11, stile = (m0 >> 7) & 15;
    pmax[(size_t)(b * 16 + stile) * EMBED + n] = m + out_b[n];
  }
}

// ---------------------------------------------------------------------------
// Kernel F1: ctx max-reduce + MLP layer1 slice. Grid 32 = (b<<3)|chunk.
// Each block: ctx[b] (512) from pmax, then 64 outputs of layer1.
// ---------------------------------------------------------------------------
__global__ __launch_bounds__(256) void mlp_ctx_l1(
    const float* __restrict__ pmax, const float* __restrict__ w1,
    const float* __restrict__ b1, float* __restrict__ h1g) {
  __shared__ float ctx[512];
  const int b = blockIdx.x >> 3, chunk = blockIdx.x & 7;
  const int tid = threadIdx.x;

  for (int e = tid; e < 512; e += 256) {
    float m = -1e30f;
#pragma unroll
    for (int t = 0; t < 16; ++t) m = fmaxf(m, pmax[(size_t)(b * 16 + t) * 512 + e]);
    ctx[e] = m;
  }
  __syncthreads();

  const int o = chunk * 64 + (tid >> 2), kq = tid & 3;  // 4 threads per out, 128 k each
  float acc = 0.f;
  const float* wr = w1 + (size_t)o * 512 + kq * 128;
  const float* xr = ctx + kq * 128;
  for (int k = 0; k < 128; k += 4) {
    const float4 wv = *(const float4*)(wr + k);
    const float4 xv = *(const float4*)(xr + k);
    acc += wv.x * xv.x + wv.y * xv.y + wv.z * xv.z + wv.w * xv.w;
  }
  acc += __shfl_xor(acc, 1);
  acc += __shfl_xor(acc, 2);
  if (kq == 0) {
    const float a = acc + b1[o];
    h1g[b * 512 + o] = a > 0.f ? a : 0.01f * a;
  }
}

// ---------------------------------------------------------------------------
// Kernel F2: MLP layer2 slice. Grid 16 = (b<<2)|chunk. 64 outs per block.
// ---------------------------------------------------------------------------
__global__ __launch_bounds__(256) void mlp_l2(
    const float* __restrict__ h1g, const float* __restrict__ w2,
    const float* __restrict__ b2, float* __restrict__ h2g) {
  __shared__ float xb[512];
  const int b = blockIdx.x >> 2, chunk = blockIdx.x & 3;
  const int tid = threadIdx.x;
  for (int e = tid; e < 512; e += 256) xb[e] = h1g[b * 512 + e];
  __syncthreads();

  const int o = chunk * 64 + (tid >> 2), kq = tid & 3;
  float acc = 0.f;
  const float* wr = w2 + (size_t)o * 512 + kq * 128;
  const float* xr = xb + kq * 128;
  for (int k = 0; k < 128; k += 4) {
    const float4 wv = *(const float4*)(wr + k);
    const float4 xv = *(const float4*)(xr + k);
    acc += wv.x * xv.x + wv.y * xv.y + wv.z * xv.z + wv.w * xv.w;
  }
  acc += __shfl_xor(acc, 1);
  acc += __shfl_xor(acc, 2);
  if (kq == 0) {
    const float a = acc + b2[o];
    h2g[b * 256 + o] = a > 0.f ? a : 0.01f * a;
  }
}

// ---------------------------------------------------------------------------
// Kernel F3: MLP layer3 + layer4. Grid 4 (one block per batch).
// ---------------------------------------------------------------------------
__global__ __launch_bounds__(256) void mlp_l34(
    const float* __restrict__ h2g,
    const float* __restrict__ w3, const float* __restrict__ b3,
    const float* __restrict__ w4, const float* __restrict__ b4,
    float* __restrict__ out) {
  __shared__ float xb[256], h3[128];
  const int b = blockIdx.x, tid = threadIdx.x;
  if (tid < 256) xb[tid] = h2g[b * 256 + tid];
  __syncthreads();

  {  // layer3: 128 outs x 2 threads (128 k each)
    const int o = tid >> 1, kh = tid & 1;
    float acc = 0.f;
    const float* wr = w3 + (size_t)o * 256 + kh * 128;
    const float* xr = xb + kh * 128;
    for (int k = 0; k < 128; k += 4) {
      const float4 wv = *(const float4*)(wr + k);
      const float4 xv = *(const float4*)(xr + k);
      acc += wv.x * xv.x + wv.y * xv.y + wv.z * xv.z + wv.w * xv.w;
    }
    acc += __shfl_xor(acc, 1);
    if (kh == 0) { const float a = acc + b3[o]; h3[o] = a > 0.f ? a : 0.01f * a; }
  }
  __syncthreads();

  if (tid < 160) {  // layer4: 20 outs x 8 threads (16 k each)
    const int o = tid >> 3, ks = tid & 7;
    const float* wr = w4 + (size_t)o * 128 + ks * 16;
    const float* xr = h3 + ks * 16;
    float acc = 0.f;
    for (int k = 0; k < 16; k += 4) {
      const float4 wv = *(const float4*)(wr + k);
      const float4 xv = *(const float4*)(xr + k);
      acc += wv.x * xv.x + wv.y * xv.y + wv.z * xv.z + wv.w * xv.w;
    }
    acc += __shfl_xor(acc, 1);
    acc += __shfl_xor(acc, 2);
    acc += __shfl_xor(acc, 4);
    if (ks == 0) out[b * 20 + o] = acc + b4[o];
  }
}

// ---------------------------------------------------------------------------
extern "C" void kernel_launch(void* const* d_in, const int* in_sizes, int n_in,
                              void* d_out, int out_size, void* d_ws, size_t ws_size,
                              hipStream_t stream) {
  (void)in_sizes; (void)n_in; (void)out_size; (void)ws_size;
  const int*   text  = (const int*)d_in[0];
  const float* emb   = (const float*)d_in[1];
  const float* in_w  = (const float*)d_in[2];
  const float* in_b  = (const float*)d_in[3];
  const float* out_w = (const float*)d_in[4];
  const float* out_b = (const float*)d_in[5];
  const float* w1 = (const float*)d_in[6];
  const float* b1 = (const float*)d_in[7];
  const float* w2 = (const float*)d_in[8];
  const float* b2 = (const float*)d_in[9];
  const float* w3 = (const float*)d_in[10];
  const float* b3 = (const float*)d_in[11];
  const float* w4 = (const float*)d_in[12];
  const float* b4 = (const float*)d_in[13];

  char* ws = (char*)d_ws;
  u16* Xb   = (u16*)(ws);                       // 8192*512*2   = 8388608
  u16* Wq   = (u16*)(ws + 8388608);             // 1536*512*2   = 1572864
  u16* Wo   = (u16*)(ws + 9961472);             // 512*512*2    = 524288
  u16* qg   = (u16*)(ws + 10485760);
  u16* kg   = (u16*)(ws + 18874368);
  u16* vt   = (u16*)(ws + 27262976);
  u16* attn = (u16*)(ws + 35651584);
  float* pmax = (float*)(ws + 44040192);        // 4*16*512*4   = 131072
  float* h1g  = (float*)(ws + 44171264);        // 4*512*4      = 8192
  float* h2g  = (float*)(ws + 44179456);        // 4*256*4      = 4096

  gather_kernel<<<TOKENS, 256, 0, stream>>>(text, emb, Xb);
  convw_kernel<<<1024, 256, 0, stream>>>(in_w, out_w, Wq, Wo);
  qkv_mfma<<<dim3(64, 12), 256, 0, stream>>>(Xb, Wq, in_b, qg, kg, vt);
  attn_mfma<<<dim3(32, 32), 256, 0, stream>>>(qg, kg, vt, attn);
  outproj_mfma<<<dim3(64, 4), 256, 0, stream>>>(attn, Wo, out_b, pmax);
  mlp_ctx_l1<<<32, 256, 0, stream>>>(pmax, w1, b1, h1g);
  mlp_l2<<<16, 256, 0, stream>>>(h1g, w2, b2, h2g);
  mlp_l34<<<4, 256, 0, stream>>>(h2g, w3, b3, w4, b4, (float*)d_out);
}